// Round 9
// baseline (252.284 us; speedup 1.0000x reference)
//
#include <hip/hip_runtime.h>
#include <hip/hip_bf16.h>

typedef __attribute__((ext_vector_type(8))) short short8;
typedef __attribute__((ext_vector_type(4))) float f32x4;

#define D 256
#define MT 64
#define NW 8
#define GRID_MAIN 256     // 1 block/CU; latency hidden by DMA ring depth
#define GV 16

__device__ __forceinline__ unsigned pack2(float a, float b) {
    __hip_bfloat162 hh = __float22bfloat162_rn(make_float2(a, b));
    return *(unsigned*)&hh;
}
__device__ __forceinline__ float fast_sigmoid(float x) {
    return __builtin_amdgcn_rcpf(1.f + __expf(-x));
}
__device__ __forceinline__ void dma16(const void* g, void* lds) {
    __builtin_amdgcn_global_load_lds((const __attribute__((address_space(1))) unsigned int*)g,
                                     (__attribute__((address_space(3))) unsigned int*)lds, 16, 0, 0);
}
__device__ __forceinline__ void dma4(const void* g, void* lds) {
    __builtin_amdgcn_global_load_lds((const __attribute__((address_space(1))) unsigned int*)g,
                                     (__attribute__((address_space(3))) unsigned int*)lds, 4, 0, 0);
}

// K0: fused prep. blocks [0,128): feat_v ; [128,384): W_u->bf16 ; [384,896): zero rst
__global__ __launch_bounds__(256) void k_prep(
    const float* __restrict__ feat, const int* __restrict__ last_nodes,
    const float* __restrict__ Wv, const float* __restrict__ bv,
    const float* __restrict__ Wu, unsigned short* __restrict__ Wub,
    float* __restrict__ featv, float* __restrict__ rst, int Bseg, int nOut) {
    const int b = blockIdx.x;
    const int t = threadIdx.x;
    if (b < 128) {
        __shared__ float fln[GV][D];
        const int b0 = b * GV;
        for (int g = 0; g < GV; ++g) {
            int bb = b0 + g;
            int ln = (bb < Bseg) ? last_nodes[bb] : 0;
            fln[g][t] = feat[(long)ln * D + t];
        }
        __syncthreads();
        float acc[GV];
        float bvj = bv[t];
        #pragma unroll
        for (int g = 0; g < GV; ++g) acc[g] = bvj;
        const float* wr = Wv + (long)t * D;
        for (int k = 0; k < D; k += 4) {
            float4 w4 = *(const float4*)(wr + k);
            #pragma unroll
            for (int g = 0; g < GV; ++g) {
                acc[g] += w4.x * fln[g][k]     + w4.y * fln[g][k + 1]
                        + w4.z * fln[g][k + 2] + w4.w * fln[g][k + 3];
            }
        }
        for (int g = 0; g < GV; ++g)
            if (b0 + g < Bseg) featv[(long)(b0 + g) * D + t] = acc[g];
    } else if (b < 384) {
        int i = (b - 128) * 256 + t;
        if (i < D * D) Wub[i] = (unsigned short)(pack2(Wu[i], 0.f) & 0xffffu);
    } else {
        int base = (b - 384) * 1024 + t;
        #pragma unroll
        for (int it = 0; it < 4; ++it) {
            int i = base + it * 256;
            if (i < nOut) rst[i] = 0.f;
        }
    }
}

// K2: persistent fused kernel. fp32 feat via global_load_lds into a 4x32KB ring
// (two K-halves x 2 tiles in flight). Granule swizzle: logical 16B-granule g of
// row r stored at physical g ^ (r&7) (applied by pre-swizzling the DMA source).
// One counted vmcnt wait per iteration; no drains in steady state.
__global__ __launch_bounds__(512, 2) void k_main(
    const float* __restrict__ feat, const float* __restrict__ cnt,
    const int* __restrict__ seg, const unsigned short* __restrict__ Wub,
    const float* __restrict__ featv, const float* __restrict__ we,
    float* __restrict__ rst, int N) {

    __shared__ float ring[4][MT * 128];    // 128 KB
    __shared__ int   seg_s[2][MT];
    __shared__ float cnt_s[2][MT];
    __shared__ float e_s[NW][MT];
    __shared__ float alpha_s[MT];

    const int t  = threadIdx.x;
    const int w  = t >> 6;
    const int l  = t & 63;
    const int rl = l & 15;
    const int h  = l >> 4;

    const int T   = (N + MT - 1) / MT;
    const int nb  = gridDim.x;
    const int per = T / nb, rem = T % nb;
    const int bid = blockIdx.x;
    const int c0  = bid * per + (bid < rem ? bid : rem);
    const int c1  = c0 + per + (bid < rem ? 1 : 0);
    if (c0 >= c1) return;

    // batch issue: [seg, cnt] dma4 first (oldest), then 8 feat dma16.
    // per-wave vmem/tile = 10.
#define STAGE_BATCH(sl, n0base)                                               \
    {                                                                         \
        long nsx = (n0base) + l; if (nsx > (long)N - 1) nsx = (long)N - 1;    \
        dma4(seg + nsx, &seg_s[(sl)][0]);                                     \
        dma4(cnt + nsx, &cnt_s[(sl)][0]);                                     \
        _Pragma("unroll")                                                     \
        for (int q = 0; q < 4; ++q) {                                         \
            int ii = w + 8 * q;                                               \
            int rr = 2 * ii + (l >> 5);                                       \
            long nn = (n0base) + rr; if (nn > (long)N - 1) nn = (long)N - 1;  \
            const float* srcp = feat + nn * D + 4 * ((l & 31) ^ (rr & 7));    \
            dma16(srcp,       &ring[2 * (sl)][ii * 256]);                     \
            dma16(srcp + 128, &ring[2 * (sl) + 1][ii * 256]);                 \
        }                                                                     \
    }

    // W_u rows [32w, 32w+32) resident in registers (proven layout, r4-r8)
    short8 a_reg[2][8];
    {
        const unsigned short* ab = Wub + (long)(32 * w + rl) * D + h * 8;
        #pragma unroll
        for (int mt = 0; mt < 2; ++mt)
            #pragma unroll
            for (int s = 0; s < 8; ++s)
                a_reg[mt][s] = *(const short8*)(ab + (long)mt * 16 * D + s * 32);
    }
    f32x4 wev[2];
    wev[0] = *(const f32x4*)(we + 32 * w + h * 4);
    wev[1] = *(const f32x4*)(we + 32 * w + 16 + h * 4);

    // ---- prologue: batch(c0); retire its seg/cnt; fv(c0); batch(c0+1) ----
    f32x4 fvr[2][4];
    STAGE_BATCH(0, (long)c0 * MT);
    asm volatile("" ::: "memory");
    asm volatile("s_waitcnt vmcnt(8)" ::: "memory");   // seg/cnt(c0) ready
    {
        #pragma unroll
        for (int nt = 0; nt < 4; ++nt) {
            int sg = seg_s[0][nt * 16 + rl];
            const float* fb = featv + (long)sg * D + 32 * w + h * 4;
            fvr[0][nt] = *(const f32x4*)(fb);
            fvr[1][nt] = *(const f32x4*)(fb + 16);
        }
    }
    asm volatile("" ::: "memory");
    if (c0 + 1 < c1) STAGE_BATCH(1, (long)(c0 + 1) * MT);
    asm volatile("" ::: "memory");

    int slot = 0;
    for (int tt = c0; tt < c1; ++tt, slot ^= 1) {
        const long n0 = (long)tt * MT;
        const bool more1 = (tt + 1 < c1);

        // single counted wait: retires ring(t), fvr(t), seg/cnt(t+1);
        // leaves batch(t+1)'s 8 feat dma16 in flight.
        if (more1) asm volatile("s_waitcnt vmcnt(8)" ::: "memory");
        else       asm volatile("s_waitcnt vmcnt(0)" ::: "memory");
        asm volatile("s_barrier" ::: "memory");

        const float* bufL = &ring[2 * slot][0];
        const float* bufH = &ring[2 * slot + 1][0];
        const int* seg_t = seg_s[slot];

        // MFMA: u[j][node]; A from regs, B repacked from fp32 swizzled LDS
        f32x4 acc[2][4];
        #pragma unroll
        for (int mt = 0; mt < 2; ++mt)
            #pragma unroll
            for (int nt = 0; nt < 4; ++nt) acc[mt][nt] = (f32x4)0.f;

        __builtin_amdgcn_s_setprio(1);
        #pragma unroll
        for (int s = 0; s < 8; ++s) {
            const float* B = (s < 4) ? bufL : bufH;
            const int s4 = s & 3;
            short8 bfr[4];
            #pragma unroll
            for (int nt = 0; nt < 4; ++nt) {
                int R  = nt * 16 + rl;
                int g1 = 8 * s4 + 2 * h;
                f32x4 lo = *(const f32x4*)(B + R * 128 + (((g1)     ^ (R & 7)) << 2));
                f32x4 hi = *(const f32x4*)(B + R * 128 + (((g1 + 1) ^ (R & 7)) << 2));
                union { unsigned u[4]; short8 s8; } cv;
                cv.u[0] = pack2(lo[0], lo[1]); cv.u[1] = pack2(lo[2], lo[3]);
                cv.u[2] = pack2(hi[0], hi[1]); cv.u[3] = pack2(hi[2], hi[3]);
                bfr[nt] = cv.s8;
            }
            #pragma unroll
            for (int mt = 0; mt < 2; ++mt)
                #pragma unroll
                for (int nt = 0; nt < 4; ++nt)
                    acc[mt][nt] = __builtin_amdgcn_mfma_f32_16x16x32_bf16(a_reg[mt][s], bfr[nt], acc[mt][nt], 0, 0, 0);
        }
        __builtin_amdgcn_s_setprio(0);

        // featv prefetch for tile t+1 (issued BEFORE batch(t+2) -> FIFO keeps
        // next iter's vmcnt(8) counted, never a drain)
        f32x4 fvn[2][4];
        if (more1) {
            const int* sn = seg_s[slot ^ 1];
            #pragma unroll
            for (int nt = 0; nt < 4; ++nt) {
                int sg = sn[nt * 16 + rl];
                const float* fb = featv + (long)sg * D + 32 * w + h * 4;
                fvn[0][nt] = *(const f32x4*)(fb);
                fvn[1][nt] = *(const f32x4*)(fb + 16);
            }
            asm volatile("" ::: "memory");
        }

        // epilogue: e partials; lane's j = 32w + 16mt + 4h + r, node = 16nt + rl
        float ep[4] = {0.f, 0.f, 0.f, 0.f};
        #pragma unroll
        for (int mt = 0; mt < 2; ++mt)
            #pragma unroll
            for (int nt = 0; nt < 4; ++nt)
                #pragma unroll
                for (int r = 0; r < 4; ++r)
                    ep[nt] += wev[mt][r] * fast_sigmoid(acc[mt][nt][r] + fvr[mt][nt][r]);
        #pragma unroll
        for (int nt = 0; nt < 4; ++nt) {
            ep[nt] += __shfl_xor(ep[nt], 16);
            ep[nt] += __shfl_xor(ep[nt], 32);
        }
        if (h == 0) {
            #pragma unroll
            for (int nt = 0; nt < 4; ++nt) e_s[w][nt * 16 + rl] = ep[nt];
        }
        asm volatile("s_waitcnt lgkmcnt(0)\ns_barrier" ::: "memory");   // b1

        if (t < MT) {
            float e = 0.f;
            #pragma unroll
            for (int q = 0; q < NW; ++q) e += e_s[q][t];
            alpha_s[t] = ((long)n0 + t < N) ? e * cnt_s[slot][t] : 0.f;
        }
        asm volatile("s_waitcnt lgkmcnt(0)\ns_barrier" ::: "memory");   // b2

        // P4: segment-sum from exact fp32 ring; thread (gq,p): rows [16gq,+16),
        // dims {2p, 2p+1}; K-half by p>=64.
        {
            const int p   = t & 127;
            const int gq  = t >> 7;
            const int i0  = gq * 16;
            const int nv  = (int)(((long)N - n0 < MT) ? ((long)N - n0) : MT);
            const int i1  = (i0 + 16 < nv) ? i0 + 16 : nv;
            const float* Bp = (p < 64) ? bufL : bufH;
            const int p6 = p & 63;
            if (i0 < i1) {
                if ((i1 - i0) == 16 && seg_t[i0] == seg_t[i1 - 1]) {
                    float ca = 0.f, cb = 0.f, ca2 = 0.f, cb2 = 0.f;
                    #pragma unroll
                    for (int i2 = 0; i2 < 16; i2 += 2) {
                        int i = i0 + i2;
                        float2 v0 = *(const float2*)(Bp + (i)     * 128 + ((((p6 >> 1) ^ ((i)     & 7))) << 2) + (p & 1) * 2);
                        float2 v1 = *(const float2*)(Bp + (i + 1) * 128 + ((((p6 >> 1) ^ ((i + 1) & 7))) << 2) + (p & 1) * 2);
                        float a0 = alpha_s[i], a1 = alpha_s[i + 1];
                        ca  += v0.x * a0; cb  += v0.y * a0;
                        ca2 += v1.x * a1; cb2 += v1.y * a1;
                    }
                    long rb = (long)seg_t[i0] * D + 2 * p;
                    atomicAdd(&rst[rb],     ca + ca2);
                    atomicAdd(&rst[rb + 1], cb + cb2);
                } else {
                    float ca = 0.f, cb = 0.f;
                    int curseg = seg_t[i0];
                    for (int i = i0; i < i1; ++i) {
                        int sgi = seg_t[i];
                        if (sgi != curseg) {
                            long rb = (long)curseg * D + 2 * p;
                            atomicAdd(&rst[rb], ca); atomicAdd(&rst[rb + 1], cb);
                            ca = cb = 0.f; curseg = sgi;
                        }
                        float2 v = *(const float2*)(Bp + i * 128 + ((((p6 >> 1) ^ (i & 7))) << 2) + (p & 1) * 2);
                        float al = alpha_s[i];
                        ca += v.x * al; cb += v.y * al;
                    }
                    long rb = (long)curseg * D + 2 * p;
                    atomicAdd(&rst[rb], ca); atomicAdd(&rst[rb + 1], cb);
                }
            }
        }
        asm volatile("s_waitcnt lgkmcnt(0)\ns_barrier" ::: "memory");   // b3

        // re-fill the slot just consumed with tile t+2
        if (tt + 2 < c1) {
            STAGE_BATCH(slot, (long)(tt + 2) * MT);
            asm volatile("" ::: "memory");
        }
        if (more1) {
            #pragma unroll
            for (int mt = 0; mt < 2; ++mt)
                #pragma unroll
                for (int nt = 0; nt < 4; ++nt) fvr[mt][nt] = fvn[mt][nt];
        }
    }
#undef STAGE_BATCH
}

extern "C" void kernel_launch(void* const* d_in, const int* in_sizes, int n_in,
                              void* d_out, int out_size, void* d_ws, size_t ws_size,
                              hipStream_t stream) {
    const float* feat = (const float*)d_in[0];
    const float* cnt  = (const float*)d_in[1];
    const int*   segp = (const int*)d_in[2];
    const int*   last = (const int*)d_in[3];
    const float* Wu   = (const float*)d_in[4];
    const float* Wv   = (const float*)d_in[5];
    const float* bv   = (const float*)d_in[6];
    const float* we   = (const float*)d_in[7];
    float* rst = (float*)d_out;

    const int N    = in_sizes[1];
    const int Bseg = in_sizes[3];

    unsigned short* Wub   = (unsigned short*)d_ws;
    float*          featv = (float*)((char*)d_ws + (size_t)D * D * sizeof(unsigned short));

    k_prep<<<896, 256, 0, stream>>>(feat, last, Wv, bv, Wu, Wub, featv, rst, Bseg, out_size);
    k_main<<<GRID_MAIN, 512, 0, stream>>>(feat, cnt, segp, Wub, featv, we, rst, N);
}

// Round 10
// 192.046 us; speedup vs baseline: 1.3137x; 1.3137x over previous
//
#include <hip/hip_runtime.h>
#include <hip/hip_bf16.h>

typedef __attribute__((ext_vector_type(8))) short short8;
typedef __attribute__((ext_vector_type(4))) float f32x4;

#define D 256
#define MT 64
#define NW 8
#define GRID_MAIN 256
#define GV 16

__device__ __forceinline__ unsigned pack2(float a, float b) {
    __hip_bfloat162 hh = __float22bfloat162_rn(make_float2(a, b));
    return *(unsigned*)&hh;
}
__device__ __forceinline__ float fast_sigmoid(float x) {
    return __builtin_amdgcn_rcpf(1.f + __expf(-x));
}
__device__ __forceinline__ void dma16(const void* g, void* lds) {
    __builtin_amdgcn_global_load_lds((const __attribute__((address_space(1))) unsigned int*)g,
                                     (__attribute__((address_space(3))) unsigned int*)lds, 16, 0, 0);
}
__device__ __forceinline__ void dma4(const void* g, void* lds) {
    __builtin_amdgcn_global_load_lds((const __attribute__((address_space(1))) unsigned int*)g,
                                     (__attribute__((address_space(3))) unsigned int*)lds, 4, 0, 0);
}

// K0: fused prep. blocks [0,128): feat_v ; [128,384): W_u->bf16 ; [384,...): zero rst
__global__ __launch_bounds__(256) void k_prep(
    const float* __restrict__ feat, const int* __restrict__ last_nodes,
    const float* __restrict__ Wv, const float* __restrict__ bv,
    const float* __restrict__ Wu, unsigned short* __restrict__ Wub,
    float* __restrict__ featv, float* __restrict__ rst, int Bseg, int nOut) {
    const int b = blockIdx.x;
    const int t = threadIdx.x;
    if (b < 128) {
        __shared__ float fln[GV][D];
        const int b0 = b * GV;
        for (int g = 0; g < GV; ++g) {
            int bb = b0 + g;
            int ln = (bb < Bseg) ? last_nodes[bb] : 0;
            fln[g][t] = feat[(long)ln * D + t];
        }
        __syncthreads();
        float acc[GV];
        float bvj = bv[t];
        #pragma unroll
        for (int g = 0; g < GV; ++g) acc[g] = bvj;
        const float* wr = Wv + (long)t * D;
        for (int k = 0; k < D; k += 4) {
            float4 w4 = *(const float4*)(wr + k);
            #pragma unroll
            for (int g = 0; g < GV; ++g) {
                acc[g] += w4.x * fln[g][k]     + w4.y * fln[g][k + 1]
                        + w4.z * fln[g][k + 2] + w4.w * fln[g][k + 3];
            }
        }
        for (int g = 0; g < GV; ++g)
            if (b0 + g < Bseg) featv[(long)(b0 + g) * D + t] = acc[g];
    } else if (b < 384) {
        int i = (b - 128) * 256 + t;
        if (i < D * D) Wub[i] = (unsigned short)(pack2(Wu[i], 0.f) & 0xffffu);
    } else {
        int base = (b - 384) * 1024 + t;
        #pragma unroll
        for (int it = 0; it < 4; ++it) {
            int i = base + it * 256;
            if (i < nOut) rst[i] = 0.f;
        }
    }
}

// K2: persistent fused kernel.
//   DMA(t+1) streams fp32 feat -> linear stage across a FULL iteration;
//   convert (post-P4) builds the bf16 XOR-swizzled tile for iter t+1;
//   MFMA/epilogue/P4 are the round-4 proven code paths.
// vmem FIFO per wave & iter: [fvr:8][def-atomics:2][dma4:2, dma16:8]
//   iter-top vmcnt(8) retires fvr+atomics+dma4 (all ancient), keeps dma16;
//   pre-convert vmcnt(0) retires the dma16 that streamed all iteration.
__global__ __launch_bounds__(512, 2) void k_main(
    const float* __restrict__ feat, const float* __restrict__ cnt,
    const int* __restrict__ seg, const unsigned short* __restrict__ Wub,
    const float* __restrict__ featv, const float* __restrict__ we,
    float* __restrict__ rst, int N) {

    __shared__ float stageF[MT][D];              // 64 KB, linear (DMA dest)
    __shared__ unsigned short Abuf[2][MT][D];    // 64 KB, swizzled bf16
    __shared__ int   seg_s[4][MT];               // 1 KB (4 slots: race-free)
    __shared__ float cnt_s[4][MT];               // 1 KB
    __shared__ float e_s[NW][MT];                // 2 KB
    __shared__ float alpha_s[MT];

    const int t  = threadIdx.x;
    const int w  = t >> 6;
    const int l  = t & 63;
    const int rl = l & 15;
    const int h  = l >> 4;

    const int T   = (N + MT - 1) / MT;
    const int nb  = gridDim.x;
    const int per = T / nb, rem = T % nb;
    const int bid = blockIdx.x;
    const int c0  = bid * per + (bid < rem ? bid : rem);
    const int c1  = c0 + per + (bid < rem ? 1 : 0);
    if (c0 >= c1) return;

    // issue order inside STAGE: dma4 seg, dma4 cnt, 8x dma16 feat (FIFO matters)
#define STAGE(ti)                                                             \
    {                                                                         \
        const long nb0 = (long)(ti) * MT;                                     \
        long nsx = nb0 + l; if (nsx > (long)N - 1) nsx = (long)N - 1;         \
        dma4(seg + nsx, &seg_s[(ti) & 3][0]);                                 \
        dma4(cnt + nsx, &cnt_s[(ti) & 3][0]);                                 \
        asm volatile("" ::: "memory");                                        \
        _Pragma("unroll")                                                     \
        for (int i = 0; i < 8; ++i) {                                         \
            int r = w + 8 * i;                                                \
            long nn = nb0 + r; if (nn > (long)N - 1) nn = (long)N - 1;        \
            dma16(feat + nn * D + 4 * l, &stageF[r][0]);                      \
        }                                                                     \
    }

    // convert wave-local rows: linear fp32 stage -> swizzled bf16 Abuf[buf]
#define CONVERT(buf)                                                          \
    {                                                                         \
        _Pragma("unroll")                                                     \
        for (int i = 0; i < 8; ++i) {                                         \
            int r = w + 8 * i;                                                \
            f32x4 fv = *(const f32x4*)&stageF[r][4 * l];                      \
            *(uint2*)&Abuf[buf][r][(((l >> 1) ^ (r & 7)) << 3) + ((l & 1) << 2)] = \
                make_uint2(pack2(fv[0], fv[1]), pack2(fv[2], fv[3]));         \
        }                                                                     \
    }

    // W_u rows [32w, 32w+32) resident in registers (64 VGPR)
    short8 a_reg[2][8];
    {
        const unsigned short* ab = Wub + (long)(32 * w + rl) * D + h * 8;
        #pragma unroll
        for (int mt = 0; mt < 2; ++mt)
            #pragma unroll
            for (int s = 0; s < 8; ++s)
                a_reg[mt][s] = *(const short8*)(ab + (long)mt * 16 * D + s * 32);
    }
    f32x4 wev[2];
    wev[0] = *(const f32x4*)(we + 32 * w + h * 4);
    wev[1] = *(const f32x4*)(we + 32 * w + 16 + h * 4);

    // ---- prologue ----
    f32x4 fvr[2][4];
    STAGE(c0);
    asm volatile("s_waitcnt vmcnt(0)" ::: "memory");
    CONVERT(c0 & 1);
    {
        #pragma unroll
        for (int nt = 0; nt < 4; ++nt) {
            int sg = seg_s[c0 & 3][nt * 16 + rl];
            const float* fb = featv + (long)sg * D + 32 * w + h * 4;
            fvr[0][nt] = *(const f32x4*)(fb);
            fvr[1][nt] = *(const f32x4*)(fb + 16);
        }
    }
    asm volatile("" ::: "memory");
    if (c0 + 1 < c1) STAGE(c0 + 1);
    asm volatile("s_waitcnt lgkmcnt(0)\ns_barrier" ::: "memory");

    for (int tt = c0; tt < c1; ++tt) {
        const long n0 = (long)tt * MT;
        const bool more1 = (tt + 1 < c1);
        const bool more2 = (tt + 2 < c1);
        const int  cur   = tt & 1;
        const int* seg_t = seg_s[tt & 3];

        // step1: counted wait — retires fvr(t)/atomics(t-1)/seg+cnt(t+1);
        //        leaves the 8 feat dma16(t+1) streaming.
        if (more1) asm volatile("s_waitcnt vmcnt(8)" ::: "memory");
        else       asm volatile("s_waitcnt vmcnt(0)" ::: "memory");

        // step2: MFMA u[j][node]; A from regs, B from bf16 swizzled LDS
        f32x4 acc[2][4];
        #pragma unroll
        for (int mt = 0; mt < 2; ++mt)
            #pragma unroll
            for (int nt = 0; nt < 4; ++nt) acc[mt][nt] = (f32x4)0.f;

        const unsigned short* Ab = &Abuf[cur][0][0];
        #pragma unroll
        for (int s = 0; s < 8; ++s) {
            short8 bfr[4];
            #pragma unroll
            for (int nt = 0; nt < 4; ++nt) {
                int R  = nt * 16 + rl;
                int gr = (s * 4 + h) ^ (rl & 7);
                bfr[nt] = *(const short8*)(Ab + R * D + gr * 8);
            }
            #pragma unroll
            for (int mt = 0; mt < 2; ++mt)
                #pragma unroll
                for (int nt = 0; nt < 4; ++nt)
                    acc[mt][nt] = __builtin_amdgcn_mfma_f32_16x16x32_bf16(a_reg[mt][s], bfr[nt], acc[mt][nt], 0, 0, 0);
        }

        // step3: epilogue; lane's j = 32w + 16mt + 4h + r, node = 16nt + rl
        float ep[4] = {0.f, 0.f, 0.f, 0.f};
        #pragma unroll
        for (int mt = 0; mt < 2; ++mt)
            #pragma unroll
            for (int nt = 0; nt < 4; ++nt)
                #pragma unroll
                for (int r = 0; r < 4; ++r)
                    ep[nt] += wev[mt][r] * fast_sigmoid(acc[mt][nt][r] + fvr[mt][nt][r]);
        #pragma unroll
        for (int nt = 0; nt < 4; ++nt) {
            ep[nt] += __shfl_xor(ep[nt], 16);
            ep[nt] += __shfl_xor(ep[nt], 32);
        }
        if (h == 0) {
            #pragma unroll
            for (int nt = 0; nt < 4; ++nt) e_s[w][nt * 16 + rl] = ep[nt];
        }
        asm volatile("s_waitcnt lgkmcnt(0)\ns_barrier" ::: "memory");   // b1

        // step4: alpha (zero for OOB rows)
        if (t < MT) {
            float e = 0.f;
            #pragma unroll
            for (int q = 0; q < NW; ++q) e += e_s[q][t];
            alpha_s[t] = (n0 + t < N) ? e * cnt_s[tt & 3][t] : 0.f;
        }
        asm volatile("s_waitcnt lgkmcnt(0)\ns_barrier" ::: "memory");   // b2

        // step4.5: fvr(t+1) — seg(t+1) retired at step1; window = P4 + convert
        if (more1) {
            const int* sn = seg_s[(tt + 1) & 3];
            #pragma unroll
            for (int nt = 0; nt < 4; ++nt) {
                int sg = sn[nt * 16 + rl];
                const float* fb = featv + (long)sg * D + 32 * w + h * 4;
                fvr[0][nt] = *(const f32x4*)(fb);
                fvr[1][nt] = *(const f32x4*)(fb + 16);
            }
            asm volatile("" ::: "memory");
        }

        // step5: P4 segment-sum from bf16 tile; final atomic pair DEFERRED
        long rb_p = -1; float ca_p = 0.f, cb_p = 0.f;
        {
            const int p   = t & 127;
            const int gq  = t >> 7;
            const int i0  = gq * 16;
            const int nv  = (int)(((long)N - n0 < MT) ? ((long)N - n0) : MT);
            const int i1  = (i0 + 16 < nv) ? (i0 + 16) : nv;
            const unsigned* Ab32 = (const unsigned*)Ab;
            if (i0 < i1) {
                if ((i1 - i0) == 16 && seg_t[i0] == seg_t[i1 - 1]) {
                    float ca = 0.f, cb = 0.f, ca2 = 0.f, cb2 = 0.f;
                    #pragma unroll
                    for (int i2 = 0; i2 < 16; i2 += 2) {
                        int i = i0 + i2;
                        unsigned v0 = Ab32[(i + 0) * 128 + (((p >> 2) ^ ((i + 0) & 7)) << 2) + (p & 3)];
                        unsigned v1 = Ab32[(i + 1) * 128 + (((p >> 2) ^ ((i + 1) & 7)) << 2) + (p & 3)];
                        float a0 = alpha_s[i + 0], a1 = alpha_s[i + 1];
                        ca  += __uint_as_float(v0 << 16) * a0;
                        cb  += __uint_as_float(v0 & 0xffff0000u) * a0;
                        ca2 += __uint_as_float(v1 << 16) * a1;
                        cb2 += __uint_as_float(v1 & 0xffff0000u) * a1;
                    }
                    rb_p = (long)seg_t[i0] * D + 2 * p;
                    ca_p = ca + ca2; cb_p = cb + cb2;
                } else {
                    float ca = 0.f, cb = 0.f;
                    int curseg = seg_t[i0];
                    for (int i = i0; i < i1; ++i) {
                        int sgi = seg_t[i];
                        if (sgi != curseg) {                 // rare interior flush
                            long rb = (long)curseg * D + 2 * p;
                            atomicAdd(&rst[rb], ca); atomicAdd(&rst[rb + 1], cb);
                            ca = cb = 0.f; curseg = sgi;
                        }
                        unsigned v = Ab32[i * 128 + (((p >> 2) ^ (i & 7)) << 2) + (p & 3)];
                        float al = alpha_s[i];
                        ca += __uint_as_float(v << 16) * al;
                        cb += __uint_as_float(v & 0xffff0000u) * al;
                    }
                    rb_p = (long)curseg * D + 2 * p;
                    ca_p = ca; cb_p = cb;
                }
            }
        }
        asm volatile("" ::: "memory");

        // step6/7: retire feat dma16(t+1) (streamed all iteration), convert
        if (more1) {
            asm volatile("s_waitcnt vmcnt(0)" ::: "memory");
            CONVERT((tt + 1) & 1);
        }

        // step7.5: deferred atomics (after the vmcnt(0) -> never waited fresh)
        if (rb_p >= 0) {
            atomicAdd(&rst[rb_p], ca_p);
            atomicAdd(&rst[rb_p + 1], cb_p);
        }
        asm volatile("" ::: "memory");

        // step8: issue DMA for tile t+2 (streams across all of iter t+1)
        if (more2) {
            STAGE(tt + 2);
            asm volatile("" ::: "memory");
        }

        // step9: close iteration (convert writes visible; stage/slots safe)
        asm volatile("s_waitcnt lgkmcnt(0)\ns_barrier" ::: "memory");   // b3
    }
#undef STAGE
#undef CONVERT
}

extern "C" void kernel_launch(void* const* d_in, const int* in_sizes, int n_in,
                              void* d_out, int out_size, void* d_ws, size_t ws_size,
                              hipStream_t stream) {
    const float* feat = (const float*)d_in[0];
    const float* cnt  = (const float*)d_in[1];
    const int*   segp = (const int*)d_in[2];
    const int*   last = (const int*)d_in[3];
    const float* Wu   = (const float*)d_in[4];
    const float* Wv   = (const float*)d_in[5];
    const float* bv   = (const float*)d_in[6];
    const float* we   = (const float*)d_in[7];
    float* rst = (float*)d_out;

    const int N    = in_sizes[1];
    const int Bseg = in_sizes[3];

    unsigned short* Wub   = (unsigned short*)d_ws;
    float*          featv = (float*)((char*)d_ws + (size_t)D * D * sizeof(unsigned short));

    const int zero_blocks = (out_size + 1023) / 1024;
    k_prep<<<384 + zero_blocks, 256, 0, stream>>>(feat, last, Wv, bv, Wu, Wub, featv, rst, Bseg, out_size);
    k_main<<<GRID_MAIN, 512, 0, stream>>>(feat, cnt, segp, Wub, featv, we, rst, N);
}